// Round 4
// baseline (11.862 us; speedup 1.0000x reference)
//
#include <hip/hip_runtime.h>

// PulseLoss fused single-node kernel for MI355X — round 4.
//
// Math facts exploited:
//  - K(d) = exp(-d^2/8) underflows f32 for |d| >= 29 -> each 1024-elem chunk
//    only needs target peaks in a +-32 halo; peaks sparse (~2/chunk).
//  - clamped LDS table lookup (K[+-33] == 0) -> branch-free gaussian gather.
//  - log clamp at -100 never fires for pred in [1e-6, 1-1e-6] (kept anyway).
//  - log1p(-p) == log(1-p) exactly in f32 (Sterbenz for p >= 0.5).
//
// Structure (round-3 post-mortem): 2-node graph was dispatch-overhead-bound
// (~2-4us per node; data costs <1us). Now ONE node: 257 blocks. Block 0 is a
// finalizer that spin-waits on 256 magic flags (stream-K fixup pattern);
// blocks 1..256 are workers (one 1024-elem chunk each). Workers release-store
// {bce partial, signed count diff, flag=MAGIC} at AGENT scope; finalizer
// acquire-spins on its flag, coherently reads the partials (sc-bit loads --
// plain loads could hit a stale cross-XCD L2 line from the previous replay),
// resets flags to 0 (so every graph replay sees non-MAGIC flags; the 0xAA
// poison is also non-MAGIC), reduces, writes the 3 outputs. No circular
// wait: workers never wait on anything, so scheduling order can't deadlock.

#define BATCH    32
#define SEQ_T    8192
#define CHUNK    1024
#define NWORK    (BATCH * (SEQ_T / CHUNK))   // 256 worker blocks
#define HALO     32
#define KTAB     67                          // d in [-33, 33]; edges are 0
#define MAXPEAKS 64
#define NTHREADS 256
#define FLAG_MAGIC 0x5CA1AB1E

// ws layout (ints/floats, 4B each):
//   [0   .. 255]  bce partials (float)
//   [256 .. 511]  signed count diffs (int)
//   [512 .. 767]  flags (int)

__global__ __launch_bounds__(NTHREADS) void pulse_loss_one(
    const float* __restrict__ pred,
    const float* __restrict__ tgt,
    float* __restrict__ out,
    float* __restrict__ ws)
{
    const int tid = threadIdx.x;
    float* ws_f = ws;
    int*   ws_i = (int*)ws;

    if (blockIdx.x == 0) {
        // ---------------- finalizer block ----------------
        int* flags = ws_i + 2 * NWORK;
        const int t = tid;   // one partial per thread (NTHREADS == NWORK)

        while (__hip_atomic_load(&flags[t], __ATOMIC_ACQUIRE,
                                 __HIP_MEMORY_SCOPE_AGENT) != FLAG_MAGIC) {
            __builtin_amdgcn_s_sleep(2);
        }
        float bce = __hip_atomic_load(&ws_f[t], __ATOMIC_RELAXED,
                                      __HIP_MEMORY_SCOPE_AGENT);
        int   dc  = __hip_atomic_load(&ws_i[NWORK + t], __ATOMIC_RELAXED,
                                      __HIP_MEMORY_SCOPE_AGENT);
        // reset flag so the next replay (and any call after the 0xAA poison)
        // starts from a non-MAGIC state
        __hip_atomic_store(&flags[t], 0, __ATOMIC_RELAXED,
                           __HIP_MEMORY_SCOPE_AGENT);

        // dcnt: 8 consecutive chunk slots per row -> segmented 8-wide sum, |.|
        dc += __shfl_down(dc, 4, 8);
        dc += __shfl_down(dc, 2, 8);
        dc += __shfl_down(dc, 1, 8);
        float ad = ((t & 7) == 0) ? fabsf((float)dc) : 0.0f;

        #pragma unroll
        for (int off = 32; off > 0; off >>= 1) {
            bce += __shfl_down(bce, off);
            ad  += __shfl_down(ad,  off);
        }

        __shared__ float s_b[4], s_a[4];
        const int wid  = t >> 6;
        const int lane = t & 63;
        if (lane == 0) { s_b[wid] = bce; s_a[wid] = ad; }
        __syncthreads();

        if (t == 0) {
            float sb = 0.0f, sd = 0.0f;
            #pragma unroll
            for (int w = 0; w < 4; ++w) { sb += s_b[w]; sd += s_a[w]; }
            float bce_loss   = -sb / (float)(BATCH * SEQ_T);
            float count_loss = 0.1f * sd / (float)BATCH;
            out[0] = bce_loss + count_loss;
            out[1] = bce_loss;
            out[2] = count_loss;
        }
        return;
    }

    // ---------------- worker blocks ----------------
    const int blk = blockIdx.x - 1;      // 0..255
    const int b   = blk >> 3;            // row
    const int c0  = (blk & 7) * CHUNK;   // chunk start within row
    const float* __restrict__ prow = pred + (size_t)b * SEQ_T;
    const float* __restrict__ trow = tgt  + (size_t)b * SEQ_T;

    __shared__ int   s_npeaks;
    __shared__ int   s_peaks[MAXPEAKS];  // row-global positions
    __shared__ float s_K[KTAB];
    __shared__ float s_bce[NTHREADS / 64];
    __shared__ int   s_cnt[NTHREADS / 64];

    if (tid == 0) s_npeaks = 0;
    if (tid < KTAB) {
        float d = (float)(tid - 33);
        s_K[tid] = __expf(-0.125f * d * d);  // exp(-0.5*(d/2)^2); 0 at edges
    }
    __syncthreads();

    // Phase 1: scan target over [c0-HALO, c0+CHUNK+HALO); count interior peaks.
    int cnt_t = 0;
    for (int i = tid; i < CHUNK + 2 * HALO; i += NTHREADS) {
        int gi = c0 - HALO + i;
        if (gi >= 0 && gi < SEQ_T) {
            if (trow[gi] > 0.0f) {
                int idx = atomicAdd(&s_npeaks, 1);   // LDS atomic, ~2 hits/blk
                if (idx < MAXPEAKS) s_peaks[idx] = gi;
                if (gi >= c0 && gi < c0 + CHUNK) cnt_t++;
            }
        }
    }
    __syncthreads();
    const int np = min(s_npeaks, MAXPEAKS);

    // Phase 2: one float4 of pred per thread; branch-free gaussian gather.
    const float4 p4 = ((const float4*)(prow + c0))[tid];
    float bce  = 0.0f;
    int   dcnt = -cnt_t;
    #pragma unroll
    for (int j = 0; j < 4; ++j) {
        const float p = (j == 0) ? p4.x : (j == 1) ? p4.y : (j == 2) ? p4.z : p4.w;
        const int   i = c0 + tid * 4 + j;
        float g = 0.0f;
        for (int k = 0; k < np; ++k) {
            int d = i - s_peaks[k];
            d = min(max(d, -33), 33);
            g += s_K[d + 33];            // 0 outside the true support
        }
        g = fminf(g, 1.0f);
        float lp  = fmaxf(__logf(p),        -100.0f);
        float l1p = fmaxf(__logf(1.0f - p), -100.0f);
        bce  += l1p + g * (lp - l1p);
        dcnt += (p > 0.5f) ? 1 : 0;
    }

    // Phase 3: block reduction (wave64 shuffle + LDS across 4 waves).
    #pragma unroll
    for (int off = 32; off > 0; off >>= 1) {
        bce  += __shfl_down(bce,  off);
        dcnt += __shfl_down(dcnt, off);
    }
    const int wid  = tid >> 6;
    const int lane = tid & 63;
    if (lane == 0) { s_bce[wid] = bce; s_cnt[wid] = dcnt; }
    __syncthreads();

    if (tid == 0) {
        float tb = 0.0f;
        int   tc = 0;
        #pragma unroll
        for (int w = 0; w < NTHREADS / 64; ++w) { tb += s_bce[w]; tc += s_cnt[w]; }
        // publish partials, then release the flag (AGENT scope = sc-bit ops,
        // coherent across XCD L2s)
        __hip_atomic_store(&ws_f[blk], tb, __ATOMIC_RELAXED,
                           __HIP_MEMORY_SCOPE_AGENT);
        __hip_atomic_store(&ws_i[NWORK + blk], tc, __ATOMIC_RELAXED,
                           __HIP_MEMORY_SCOPE_AGENT);
        __hip_atomic_store(&ws_i[2 * NWORK + blk], FLAG_MAGIC, __ATOMIC_RELEASE,
                           __HIP_MEMORY_SCOPE_AGENT);
    }
}

extern "C" void kernel_launch(void* const* d_in, const int* in_sizes, int n_in,
                              void* d_out, int out_size, void* d_ws, size_t ws_size,
                              hipStream_t stream) {
    const float* pred = (const float*)d_in[0];
    const float* tgt  = (const float*)d_in[1];
    float*       out  = (float*)d_out;
    float*       ws   = (float*)d_ws;

    pulse_loss_one<<<dim3(NWORK + 1), dim3(NTHREADS), 0, stream>>>(
        pred, tgt, out, ws);
}

// Round 5
// 11.628 us; speedup vs baseline: 1.0201x; 1.0201x over previous
//
#include <hip/hip_runtime.h>

// PulseLoss fused single-node kernel for MI355X — round 5: critical-path trim.
//
// Status: dur_us is dominated by a ~10us fixed graph-replay overhead
// (1-node vs 2-node graphs measured identical within noise; data = 2 MB).
// This round trims the remaining ~2us of kernel latency:
//  - all global loads (pred float4, target float4, halo) issued at kernel
//    entry, overlapping the K-table VALU work and LDS init;
//  - phase-1 target scan vectorized: 1 interior float4/thread + 16 halo
//    float4s/block (was 4.25 scalar strided iterations with bounds checks);
//  - log count cut 8 -> ~4-5 per thread:  sum log(1-p_i) = log prod(1-p_i)
//    (one __logf; products >= (1e-6)^4 >> FLT_MIN), and the g-weighted term
//    g*(log p - log(1-p)) computed only where g > 0 (~2% of lanes);
//  - the -100 clamps provably never fire for p in [1e-6, 1-1e-6]
//    (|log| <= 13.82) and are dropped.
//
// Math facts: K(d)=exp(-d^2/8) underflows f32 for |d| >= 29 -> chunk + -+32
// halo; clamped LDS table (K[+-33]==0) -> branch-free gather; peaks sparse.
//
// Structure: 257 blocks. Block 0 = finalizer, spin-waits on 256 magic flags
// (workers release-store partials+flag at AGENT scope = sc-bit ops, coherent
// across XCD L2s), resets flags for the next replay, reduces, writes out[3].
// Workers never wait -> no deadlock under any dispatch order.

#define BATCH    32
#define SEQ_T    8192
#define CHUNK    1024
#define NWORK    (BATCH * (SEQ_T / CHUNK))   // 256 worker blocks
#define HALO     32
#define KTAB     67                          // d in [-33, 33]; edges are 0
#define MAXPEAKS 64
#define NTHREADS 256
#define FLAG_MAGIC 0x5CA1AB1E

// ws layout (4B words): [0..255] bce partials (f32) | [256..511] dcnt (int)
//                       | [512..767] flags (int)

__global__ __launch_bounds__(NTHREADS) void pulse_loss_one(
    const float* __restrict__ pred,
    const float* __restrict__ tgt,
    float* __restrict__ out,
    float* __restrict__ ws)
{
    const int tid  = threadIdx.x;
    float* ws_f = ws;
    int*   ws_i = (int*)ws;

    if (blockIdx.x == 0) {
        // ---------------- finalizer block ----------------
        int* flags = ws_i + 2 * NWORK;
        const int t = tid;   // one partial per thread (NTHREADS == NWORK)

        while (__hip_atomic_load(&flags[t], __ATOMIC_ACQUIRE,
                                 __HIP_MEMORY_SCOPE_AGENT) != FLAG_MAGIC) {
            __builtin_amdgcn_s_sleep(1);
        }
        float bce = __hip_atomic_load(&ws_f[t], __ATOMIC_RELAXED,
                                      __HIP_MEMORY_SCOPE_AGENT);
        int   dc  = __hip_atomic_load(&ws_i[NWORK + t], __ATOMIC_RELAXED,
                                      __HIP_MEMORY_SCOPE_AGENT);
        // reset flag so the next graph replay starts from a non-MAGIC state
        // (0xAA poison is also non-MAGIC)
        __hip_atomic_store(&flags[t], 0, __ATOMIC_RELAXED,
                           __HIP_MEMORY_SCOPE_AGENT);

        // dcnt: 8 consecutive chunk slots per row -> segmented 8-wide sum, |.|
        dc += __shfl_down(dc, 4, 8);
        dc += __shfl_down(dc, 2, 8);
        dc += __shfl_down(dc, 1, 8);
        float ad = ((t & 7) == 0) ? fabsf((float)dc) : 0.0f;

        #pragma unroll
        for (int off = 32; off > 0; off >>= 1) {
            bce += __shfl_down(bce, off);
            ad  += __shfl_down(ad,  off);
        }

        __shared__ float s_b[4], s_a[4];
        const int wid  = t >> 6;
        const int lane = t & 63;
        if (lane == 0) { s_b[wid] = bce; s_a[wid] = ad; }
        __syncthreads();

        if (t == 0) {
            float sb = 0.0f, sd = 0.0f;
            #pragma unroll
            for (int w = 0; w < 4; ++w) { sb += s_b[w]; sd += s_a[w]; }
            float bce_loss   = -sb / (float)(BATCH * SEQ_T);
            float count_loss = 0.1f * sd / (float)BATCH;
            out[0] = bce_loss + count_loss;
            out[1] = bce_loss;
            out[2] = count_loss;
        }
        return;
    }

    // ---------------- worker blocks ----------------
    const int blk = blockIdx.x - 1;      // 0..255
    const int b   = blk >> 3;            // row
    const int c0  = (blk & 7) * CHUNK;   // chunk start within row
    const float* __restrict__ prow = pred + (size_t)b * SEQ_T;
    const float* __restrict__ trow = tgt  + (size_t)b * SEQ_T;

    __shared__ int   s_npeaks;
    __shared__ int   s_peaks[MAXPEAKS];  // row-global positions
    __shared__ float s_K[KTAB];
    __shared__ float s_bce[NTHREADS / 64];
    __shared__ int   s_cnt[NTHREADS / 64];

    // Issue ALL global loads up front; they overlap K-table VALU + LDS init.
    const int    ibase = c0 + tid * 4;
    const float4 p4 = ((const float4*)(prow + c0))[tid];
    const float4 t4 = ((const float4*)(trow + c0))[tid];
    float4 h4 = make_float4(0.0f, 0.0f, 0.0f, 0.0f);
    int    hbase = -1;
    if (tid < 16) {
        int h = (tid < 8) ? (c0 - HALO + tid * 4)
                          : (c0 + CHUNK + (tid - 8) * 4);
        if (h >= 0 && h < SEQ_T) { h4 = *(const float4*)(trow + h); hbase = h; }
    }

    if (tid == 0) s_npeaks = 0;
    if (tid < KTAB) {
        float d = (float)(tid - 33);
        s_K[tid] = __expf(-0.125f * d * d);  // exp(-0.5*(d/2)^2); 0 at edges
    }
    __syncthreads();

    // Phase 1: push peak positions (row-global) to LDS; count interior peaks.
    int cnt_t = 0;
    if (t4.x > 0.0f) { s_peaks[atomicAdd(&s_npeaks, 1) & (MAXPEAKS - 1)] = ibase;     cnt_t++; }
    if (t4.y > 0.0f) { s_peaks[atomicAdd(&s_npeaks, 1) & (MAXPEAKS - 1)] = ibase + 1; cnt_t++; }
    if (t4.z > 0.0f) { s_peaks[atomicAdd(&s_npeaks, 1) & (MAXPEAKS - 1)] = ibase + 2; cnt_t++; }
    if (t4.w > 0.0f) { s_peaks[atomicAdd(&s_npeaks, 1) & (MAXPEAKS - 1)] = ibase + 3; cnt_t++; }
    if (hbase >= 0) {
        if (h4.x > 0.0f) s_peaks[atomicAdd(&s_npeaks, 1) & (MAXPEAKS - 1)] = hbase;
        if (h4.y > 0.0f) s_peaks[atomicAdd(&s_npeaks, 1) & (MAXPEAKS - 1)] = hbase + 1;
        if (h4.z > 0.0f) s_peaks[atomicAdd(&s_npeaks, 1) & (MAXPEAKS - 1)] = hbase + 2;
        if (h4.w > 0.0f) s_peaks[atomicAdd(&s_npeaks, 1) & (MAXPEAKS - 1)] = hbase + 3;
    }
    __syncthreads();
    const int np = min(s_npeaks, MAXPEAKS);

    // Phase 2: gaussian gather (branch-free table), then BCE with minimal logs.
    float g0 = 0.0f, g1 = 0.0f, g2 = 0.0f, g3 = 0.0f;
    for (int k = 0; k < np; ++k) {
        const int pk = ibase - s_peaks[k];
        int d0 = min(max(pk,     -33), 33);
        int d1 = min(max(pk + 1, -33), 33);
        int d2 = min(max(pk + 2, -33), 33);
        int d3 = min(max(pk + 3, -33), 33);
        g0 += s_K[d0 + 33]; g1 += s_K[d1 + 33];
        g2 += s_K[d2 + 33]; g3 += s_K[d3 + 33];
    }

    const float q0 = 1.0f - p4.x, q1 = 1.0f - p4.y;
    const float q2 = 1.0f - p4.z, q3 = 1.0f - p4.w;
    // sum_j log(1-p_j) in ONE log; product >= (1e-6)^4 = 1e-24 >> FLT_MIN.
    // (-100 clamps never fire: |log| <= 13.82 for p in [1e-6, 1-1e-6].)
    float bce = __logf((q0 * q1) * (q2 * q3));
    if (g0 > 0.0f) bce += fminf(g0, 1.0f) * (__logf(p4.x) - __logf(q0));
    if (g1 > 0.0f) bce += fminf(g1, 1.0f) * (__logf(p4.y) - __logf(q1));
    if (g2 > 0.0f) bce += fminf(g2, 1.0f) * (__logf(p4.z) - __logf(q2));
    if (g3 > 0.0f) bce += fminf(g3, 1.0f) * (__logf(p4.w) - __logf(q3));

    int dcnt = ((p4.x > 0.5f) ? 1 : 0) + ((p4.y > 0.5f) ? 1 : 0)
             + ((p4.z > 0.5f) ? 1 : 0) + ((p4.w > 0.5f) ? 1 : 0) - cnt_t;

    // Phase 3: block reduction (wave64 shuffle + LDS across 4 waves).
    #pragma unroll
    for (int off = 32; off > 0; off >>= 1) {
        bce  += __shfl_down(bce,  off);
        dcnt += __shfl_down(dcnt, off);
    }
    const int wid  = tid >> 6;
    const int lane = tid & 63;
    if (lane == 0) { s_bce[wid] = bce; s_cnt[wid] = dcnt; }
    __syncthreads();

    if (tid == 0) {
        float tb = 0.0f;
        int   tc = 0;
        #pragma unroll
        for (int w = 0; w < NTHREADS / 64; ++w) { tb += s_bce[w]; tc += s_cnt[w]; }
        // publish partials, then release the flag (AGENT scope, sc-bit ops)
        __hip_atomic_store(&ws_f[blk], tb, __ATOMIC_RELAXED,
                           __HIP_MEMORY_SCOPE_AGENT);
        __hip_atomic_store(&ws_i[NWORK + blk], tc, __ATOMIC_RELAXED,
                           __HIP_MEMORY_SCOPE_AGENT);
        __hip_atomic_store(&ws_i[2 * NWORK + blk], FLAG_MAGIC, __ATOMIC_RELEASE,
                           __HIP_MEMORY_SCOPE_AGENT);
    }
}

extern "C" void kernel_launch(void* const* d_in, const int* in_sizes, int n_in,
                              void* d_out, int out_size, void* d_ws, size_t ws_size,
                              hipStream_t stream) {
    const float* pred = (const float*)d_in[0];
    const float* tgt  = (const float*)d_in[1];
    float*       out  = (float*)d_out;
    float*       ws   = (float*)d_ws;

    pulse_loss_one<<<dim3(NWORK + 1), dim3(NTHREADS), 0, stream>>>(
        pred, tgt, out, ws);
}